// Round 9
// baseline (1704.314 us; speedup 1.0000x reference)
//
#include <hip/hip_runtime.h>
#include <hip/hip_bf16.h>
#include <math.h>

#define BNEPS 1e-5f

// Chunked XCD swizzle: grid = NSBP*NOCG (NSBP = ceil(NSB/8)*8). hb%8 = XCD
// (round-robin dispatch heuristic). Per XCD: contiguous bs range, with all
// NOCG oc-groups of each bs dispatched consecutively -> input re-reads served
// by that XCD's L2 instead of HBM. Bijective; dead blocks (bs>=NSB) return.
#define XCD_DECODE(NSB_, NSBP_, NOCG_)                 \
    int hb  = blockIdx.x;                              \
    int pos = hb % (8 * (NOCG_));                      \
    int xcd = pos % 8;                                 \
    int ocg = pos / 8;                                 \
    int sg8 = hb / (8 * (NOCG_));                      \
    int bs  = xcd * ((NSBP_) / 8) + sg8;               \
    if (bs >= (NSB_)) return;

// =====================================================================
// conv1: 7x7 stride4 pad3, 3->32, fused BN+ReLU
// in : NCHW (256,3,224,224)   out: NHWC (256,56,56,32)
// Thread: 8 oc x 4 images (n0, n0+64, n0+128, n0+192).  NOCG=4, NSB=784.
// Per (ic,ky): 8 aligned dwordx4 global + 14 uniform ds_b128 -> 224 FMA.
// Row loads: ix0=4*ox-3; ix0-1=4(ox-1) and ix0+3=4*ox both 16B-aligned ->
// two aligned float4 per (img,ic,ky): head (ox>0 only; .y/.z/.w) + tail.
// Rows iy<0 (oy==0, ky<3) skipped; bottom/right never OOB (pad<stride).
// =====================================================================
__global__ __launch_bounds__(256, 2) void conv1_bn_relu(
    const float* __restrict__ in, const float* __restrict__ w,
    const float* __restrict__ cb, const float* __restrict__ bsc,
    const float* __restrict__ bbi, const float* __restrict__ bmu,
    const float* __restrict__ bva, float* __restrict__ out)
{
    XCD_DECODE(784, 784, 4);
    __shared__ float wsm[1176]; // [ic][tap][oc8]
    int tid = threadIdx.x;
    for (int i = tid; i < 1176; i += 256) {
        int o = i & 7; int t = i >> 3;
        int ic = t / 49; int tap = t % 49;
        wsm[i] = w[(ocg * 8 + o) * 147 + ic * 49 + tap];
    }
    __syncthreads();

    int sg = bs * 256 + tid;          // [0, 200704)
    int n0 = sg / 3136;               // [0,64)
    int s  = sg - n0 * 3136;
    int oy = s / 56, ox = s - oy * 56;
    int iy0 = oy * 4 - 3, ix0 = ox * 4 - 3;
    bool headok = (ox > 0);

    float acc[4][8];
    #pragma unroll
    for (int i = 0; i < 4; ++i)
        #pragma unroll
        for (int o = 0; o < 8; ++o) acc[i][o] = 0.f;

    const size_t img = (size_t)3 * 224 * 224;
    const float* base0 = in + (size_t)n0 * img;

    for (int ic = 0; ic < 3; ++ic) {
        const float* xc = base0 + (size_t)ic * 224 * 224;
        const float* wc = wsm + ic * 49 * 8;
        #pragma unroll
        for (int ky = 0; ky < 7; ++ky) {
            bool rowok = (ky >= 3) || (oy > 0);
            if (rowok) {
                int iy = iy0 + ky;
                const float* xr = xc + iy * 224;
                float r[4][7];
                #pragma unroll
                for (int i = 0; i < 4; ++i) {
                    const float* xri = xr + (size_t)i * 64 * img;
                    float4 hd = make_float4(0.f, 0.f, 0.f, 0.f);
                    if (headok) hd = *(const float4*)(xri + ix0 - 1); // aligned
                    float4 tl = *(const float4*)(xri + ix0 + 3);      // aligned
                    r[i][0] = hd.y; r[i][1] = hd.z; r[i][2] = hd.w;
                    r[i][3] = tl.x; r[i][4] = tl.y; r[i][5] = tl.z; r[i][6] = tl.w;
                }
                #pragma unroll
                for (int kx = 0; kx < 7; ++kx) {
                    const float4* wv = (const float4*)(wc + (ky * 7 + kx) * 8);
                    float4 wa = wv[0], wb = wv[1];
                    float wr[8] = {wa.x, wa.y, wa.z, wa.w, wb.x, wb.y, wb.z, wb.w};
                    #pragma unroll
                    for (int i = 0; i < 4; ++i)
                        #pragma unroll
                        for (int o = 0; o < 8; ++o)
                            acc[i][o] = fmaf(r[i][kx], wr[o], acc[i][o]);
                }
            }
        }
    }

    float scale[8], shift[8];
    #pragma unroll
    for (int o = 0; o < 8; ++o) {
        int oc = ocg * 8 + o;
        scale[o] = bsc[oc] * rsqrtf(bva[oc] + BNEPS);
        shift[o] = (cb[oc] - bmu[oc]) * scale[o] + bbi[oc];
    }
    #pragma unroll
    for (int i = 0; i < 4; ++i) {
        int n = n0 + 64 * i;
        float4 r0, r1;
        r0.x = fmaxf(fmaf(acc[i][0], scale[0], shift[0]), 0.f);
        r0.y = fmaxf(fmaf(acc[i][1], scale[1], shift[1]), 0.f);
        r0.z = fmaxf(fmaf(acc[i][2], scale[2], shift[2]), 0.f);
        r0.w = fmaxf(fmaf(acc[i][3], scale[3], shift[3]), 0.f);
        r1.x = fmaxf(fmaf(acc[i][4], scale[4], shift[4]), 0.f);
        r1.y = fmaxf(fmaf(acc[i][5], scale[5], shift[5]), 0.f);
        r1.z = fmaxf(fmaf(acc[i][6], scale[6], shift[6]), 0.f);
        r1.w = fmaxf(fmaf(acc[i][7], scale[7], shift[7]), 0.f);
        float* op = out + ((size_t)n * 3136 + s) * 32 + ocg * 8;
        *(float4*)(op)     = r0;
        *(float4*)(op + 4) = r1;
    }
}

// =====================================================================
// generic 3x3 stride2 pad1 conv, NHWC in / NHWC out, fused BN+ReLU
// Thread: 8 oc x 4 images (n0, n0+64, n0+128, n0+192).
// Per icv-step: 4 global dwordx4 + 8 uniform ds_b128 -> 128 FMA.
// OOB only top/left: ok = ((ky>0)||(oy>0)) && ((kx>0)||(ox>0))
// =====================================================================
template<int IC, int IH, int IW, int OC, int OH, int OW, int NSB, int NSBP, int NOCG>
__global__ __launch_bounds__(256, 2) void conv3x3_bn_relu_nhwc(
    const float* __restrict__ in, const float* __restrict__ w,
    const float* __restrict__ cb, const float* __restrict__ bsc,
    const float* __restrict__ bbi, const float* __restrict__ bmu,
    const float* __restrict__ bva, float* __restrict__ out)
{
    constexpr int OCPT = 8;
    constexpr int WN = 9 * IC * OCPT;
    XCD_DECODE(NSB, NSBP, NOCG);
    __shared__ float wsm[WN];         // [tap][ic][oc8]
    int tid = threadIdx.x;
    for (int i = tid; i < WN; i += 256) {
        int o = i & 7; int t = i >> 3;
        int tap = t / IC; int ic = t % IC;
        wsm[i] = w[(size_t)(ocg * OCPT + o) * IC * 9 + ic * 9 + tap];
    }
    __syncthreads();

    int sg = bs * 256 + tid;
    int n0 = sg / (OH * OW);          // [0,64)
    int s  = sg - n0 * (OH * OW);
    int oy = s / OW, ox = s - oy * OW;
    int iy0 = oy * 2 - 1, ix0 = ox * 2 - 1;

    float acc[4][OCPT];
    #pragma unroll
    for (int i = 0; i < 4; ++i)
        #pragma unroll
        for (int o = 0; o < OCPT; ++o) acc[i][o] = 0.f;

    const size_t img = (size_t)IH * IW * IC;   // NHWC elems per image
    const float* base0 = in + (size_t)n0 * img;

    #pragma unroll
    for (int ky = 0; ky < 3; ++ky) {
        #pragma unroll
        for (int kx = 0; kx < 3; ++kx) {
            bool ok = ((ky > 0) || (oy > 0)) && ((kx > 0) || (ox > 0));
            if (ok) {
                int iy = iy0 + ky, ix = ix0 + kx;
                const float* p0 = base0 + ((size_t)iy * IW + ix) * IC;
                const float* wt0 = wsm + (ky * 3 + kx) * IC * OCPT;
                for (int icv = 0; icv < IC / 4; ++icv) {
                    float4 v0 = *(const float4*)(p0 + icv * 4);
                    float4 v1 = *(const float4*)(p0 + icv * 4 + 64 * img);
                    float4 v2 = *(const float4*)(p0 + icv * 4 + 128 * img);
                    float4 v3 = *(const float4*)(p0 + icv * 4 + 192 * img);
                    float vi[4][4] = {{v0.x, v0.y, v0.z, v0.w},
                                      {v1.x, v1.y, v1.z, v1.w},
                                      {v2.x, v2.y, v2.z, v2.w},
                                      {v3.x, v3.y, v3.z, v3.w}};
                    #pragma unroll
                    for (int c = 0; c < 4; ++c) {
                        const float4* wt = (const float4*)(wt0 + (icv * 4 + c) * OCPT);
                        float4 wa = wt[0], wb = wt[1];
                        float wr[8] = {wa.x, wa.y, wa.z, wa.w, wb.x, wb.y, wb.z, wb.w};
                        #pragma unroll
                        for (int i = 0; i < 4; ++i)
                            #pragma unroll
                            for (int o = 0; o < 8; ++o)
                                acc[i][o] = fmaf(vi[i][c], wr[o], acc[i][o]);
                    }
                }
            }
        }
    }

    float scale[OCPT], shift[OCPT];
    #pragma unroll
    for (int o = 0; o < OCPT; ++o) {
        int oc = ocg * OCPT + o;
        scale[o] = bsc[oc] * rsqrtf(bva[oc] + BNEPS);
        shift[o] = (cb[oc] - bmu[oc]) * scale[o] + bbi[oc];
    }
    #pragma unroll
    for (int i = 0; i < 4; ++i) {
        int n = n0 + 64 * i;
        float* op = out + ((size_t)n * (OH * OW) + s) * OC + ocg * OCPT;
        float4 r0, r1;
        r0.x = fmaxf(fmaf(acc[i][0], scale[0], shift[0]), 0.f);
        r0.y = fmaxf(fmaf(acc[i][1], scale[1], shift[1]), 0.f);
        r0.z = fmaxf(fmaf(acc[i][2], scale[2], shift[2]), 0.f);
        r0.w = fmaxf(fmaf(acc[i][3], scale[3], shift[3]), 0.f);
        r1.x = fmaxf(fmaf(acc[i][4], scale[4], shift[4]), 0.f);
        r1.y = fmaxf(fmaf(acc[i][5], scale[5], shift[5]), 0.f);
        r1.z = fmaxf(fmaf(acc[i][6], scale[6], shift[6]), 0.f);
        r1.w = fmaxf(fmaf(acc[i][7], scale[7], shift[7]), 0.f);
        *(float4*)(op)     = r0;
        *(float4*)(op + 4) = r1;
    }
}

// =====================================================================
// avgpool NHWC (256,14,14,128) -> pooled (256,512), f = c*4 + py*2 + px
// =====================================================================
__global__ __launch_bounds__(256) void pool_kernel(
    const float* __restrict__ in, float* __restrict__ out)
{
    int i = blockIdx.x * 256 + threadIdx.x;   // 131072 total
    int n = i >> 9; int f = i & 511;
    int c = f >> 2; int py = (f >> 1) & 1; int px = f & 1;
    const float* p = in + (((size_t)n * 14 + py * 7) * 14 + px * 7) * 128 + c;
    float sum = 0.f;
    #pragma unroll
    for (int dy = 0; dy < 7; ++dy)
        #pragma unroll
        for (int dx = 0; dx < 7; ++dx) sum += p[(dy * 14 + dx) * 128];
    out[i] = sum * (1.f / 49.f);
}

// =====================================================================
// head: pre-linear + tanh*pi + 4-qubit statevector sim + post1/post2
// one wave (64 lanes) per image
// =====================================================================
__device__ __forceinline__ void q_ry(float2* st, int q, float t) {
    float s, c; sincosf(0.5f * t, &s, &c);
    int m = 1 << (3 - q);
    #pragma unroll
    for (int i = 0; i < 16; ++i) {
        if (!(i & m)) {
            float2 a0 = st[i], a1 = st[i | m];
            st[i]     = make_float2(c * a0.x - s * a1.x, c * a0.y - s * a1.y);
            st[i | m] = make_float2(s * a0.x + c * a1.x, s * a0.y + c * a1.y);
        }
    }
}
__device__ __forceinline__ void q_rx(float2* st, int q, float t) {
    float s, c; sincosf(0.5f * t, &s, &c);
    int m = 1 << (3 - q);
    #pragma unroll
    for (int i = 0; i < 16; ++i) {
        if (!(i & m)) {
            float2 a0 = st[i], a1 = st[i | m];
            st[i]     = make_float2(c * a0.x + s * a1.y, c * a0.y - s * a1.x);
            st[i | m] = make_float2(s * a0.y + c * a1.x, -s * a0.x + c * a1.y);
        }
    }
}
__device__ __forceinline__ void q_rz(float2* st, int q, float t) {
    float s, c; sincosf(0.5f * t, &s, &c);
    int m = 1 << (3 - q);
    #pragma unroll
    for (int i = 0; i < 16; ++i) {
        float2 a = st[i];
        if (i & m)  st[i] = make_float2(a.x * c - a.y * s, a.y * c + a.x * s);
        else        st[i] = make_float2(a.x * c + a.y * s, a.y * c - a.x * s);
    }
}
__device__ __forceinline__ void q_cnot(float2* st, int c, int t) {
    int mc = 1 << (3 - c), mt = 1 << (3 - t);
    #pragma unroll
    for (int i = 0; i < 16; ++i) {
        if ((i & mc) && !(i & mt)) {
            float2 tmp = st[i]; st[i] = st[i | mt]; st[i | mt] = tmp;
        }
    }
}

__global__ __launch_bounds__(64) void head_kernel(
    const float* __restrict__ h,      // (256,512)
    const float* __restrict__ pre_w, const float* __restrict__ pre_b,
    const float* __restrict__ qw,     // (2,4,3)
    const float* __restrict__ p1w, const float* __restrict__ p1b,
    const float* __restrict__ p2w, const float* __restrict__ p2b,
    float* __restrict__ out)
{
    int n = blockIdx.x;
    int lane = threadIdx.x;
    const float* hb = h + (size_t)n * 512;

    float part[4] = {0.f, 0.f, 0.f, 0.f};
    #pragma unroll
    for (int j = 0; j < 8; ++j) {
        int idx = lane * 8 + j;
        float hv = hb[idx];
        #pragma unroll
        for (int o = 0; o < 4; ++o)
            part[o] = fmaf(hv, pre_w[o * 512 + idx], part[o]);
    }
    #pragma unroll
    for (int o = 0; o < 4; ++o) {
        float p = part[o];
        #pragma unroll
        for (int off = 32; off >= 1; off >>= 1) p += __shfl_xor(p, off);
        part[o] = p;
    }
    float ang[4];
    #pragma unroll
    for (int o = 0; o < 4; ++o)
        ang[o] = tanhf(part[o] + pre_b[o]) * 3.14159265358979323846f;

    // 4-qubit statevector sim (all lanes redundantly; wave-uniform)
    float2 st[16];
    #pragma unroll
    for (int i = 0; i < 16; ++i) st[i] = make_float2(0.f, 0.f);
    st[0] = make_float2(1.f, 0.f);
    #pragma unroll
    for (int q = 0; q < 4; ++q) q_ry(st, q, ang[q]);
    #pragma unroll
    for (int l = 0; l < 2; ++l) {
        #pragma unroll
        for (int q = 0; q < 4; ++q) {
            q_rx(st, q, qw[(l * 4 + q) * 3 + 0]);
            q_ry(st, q, qw[(l * 4 + q) * 3 + 1]);
            q_rz(st, q, qw[(l * 4 + q) * 3 + 2]);
        }
        #pragma unroll
        for (int q = 0; q < 3; ++q) q_cnot(st, q, q + 1);
    }
    float ev[4];
    #pragma unroll
    for (int q = 0; q < 4; ++q) {
        int m = 1 << (3 - q);
        float e = 0.f;
        #pragma unroll
        for (int i = 0; i < 16; ++i) {
            float p = st[i].x * st[i].x + st[i].y * st[i].y;
            e += (i & m) ? -p : p;
        }
        ev[q] = e;
    }

    // post1 row per lane, relu
    float y = p1b[lane];
    #pragma unroll
    for (int o = 0; o < 4; ++o) y = fmaf(ev[o], p1w[lane * 4 + o], y);
    y = fmaxf(y, 0.f);

    // post2: 5 wave reductions
    float o5[5];
    #pragma unroll
    for (int k = 0; k < 5; ++k) {
        float p = y * p2w[k * 64 + lane];
        #pragma unroll
        for (int off = 32; off >= 1; off >>= 1) p += __shfl_xor(p, off);
        o5[k] = p;
    }
    if (lane == 0) {
        #pragma unroll
        for (int k = 0; k < 5; ++k) out[n * 5 + k] = o5[k] + p2b[k];
    }
}

// =====================================================================
extern "C" void kernel_launch(void* const* d_in, const int* in_sizes, int n_in,
                              void* d_out, int out_size, void* d_ws, size_t ws_size,
                              hipStream_t stream)
{
    const float* x   = (const float*)d_in[0];
    const float* c1w = (const float*)d_in[1];
    const float* c1b = (const float*)d_in[2];
    const float* b1s = (const float*)d_in[3];
    const float* b1b = (const float*)d_in[4];
    const float* b1m = (const float*)d_in[5];
    const float* b1v = (const float*)d_in[6];
    const float* c2w = (const float*)d_in[7];
    const float* c2b = (const float*)d_in[8];
    const float* b2s = (const float*)d_in[9];
    const float* b2b = (const float*)d_in[10];
    const float* b2m = (const float*)d_in[11];
    const float* b2v = (const float*)d_in[12];
    const float* c3w = (const float*)d_in[13];
    const float* c3b = (const float*)d_in[14];
    const float* b3s = (const float*)d_in[15];
    const float* b3b = (const float*)d_in[16];
    const float* b3m = (const float*)d_in[17];
    const float* b3v = (const float*)d_in[18];
    const float* prw = (const float*)d_in[19];
    const float* prb = (const float*)d_in[20];
    const float* qw  = (const float*)d_in[21];
    const float* p1w = (const float*)d_in[22];
    const float* p1b = (const float*)d_in[23];
    const float* p2w = (const float*)d_in[24];
    const float* p2b = (const float*)d_in[25];

    float* buf1   = (float*)d_ws;                              // NHWC (256,56,56,32)
    float* buf2   = buf1 + (size_t)256 * 3136 * 32;            // NHWC (256,28,28,64)
    float* buf3   = (float*)d_ws;                              // reuse: NHWC (256,14,14,128)
    float* pooled = buf3 + (size_t)256 * 196 * 128;            // (256,512)
    float* outp   = (float*)d_out;

    // conv1: NSB = 64*3136/256 = 784 (%8==0), NOCG=4 -> grid 3136
    hipLaunchKernelGGL(conv1_bn_relu, dim3(784 * 4), dim3(256), 0, stream,
                       x, c1w, c1b, b1s, b1b, b1m, b1v, buf1);

    // conv2: 32->64.  NSB = 64*784/256 = 196 -> NSBP=200, NOCG = 64/8 = 8
    hipLaunchKernelGGL((conv3x3_bn_relu_nhwc<32, 56, 56, 64, 28, 28, 196, 200, 8>),
                       dim3(200 * 8), dim3(256), 0, stream,
                       buf1, c2w, c2b, b2s, b2b, b2m, b2v, buf2);

    // conv3: 64->128.  NSB = 64*196/256 = 49 -> NSBP=56, NOCG = 128/8 = 16
    hipLaunchKernelGGL((conv3x3_bn_relu_nhwc<64, 28, 28, 128, 14, 14, 49, 56, 16>),
                       dim3(56 * 16), dim3(256), 0, stream,
                       buf2, c3w, c3b, b3s, b3b, b3m, b3v, buf3);

    // pool: NHWC (256,14,14,128) -> (256,512) reference order
    hipLaunchKernelGGL(pool_kernel, dim3(131072 / 256), dim3(256), 0, stream,
                       buf3, pooled);

    // head: one wave per image
    hipLaunchKernelGGL(head_kernel, dim3(256), dim3(64), 0, stream,
                       pooled, prw, prb, qw, p1w, p1b, p2w, p2b, outp);
}

// Round 12
// 1356.186 us; speedup vs baseline: 1.2567x; 1.2567x over previous
//
#include <hip/hip_runtime.h>
#include <hip/hip_bf16.h>
#include <math.h>

#define BNEPS 1e-5f

// Chunked XCD swizzle: grid = NSBP*NOCG (NSBP = ceil(NSB/8)*8). hb%8 = XCD
// (round-robin dispatch heuristic). Per XCD: contiguous bs range, with all
// NOCG oc-groups of each bs dispatched consecutively -> input re-reads served
// by that XCD's L2 instead of HBM. Bijective; dead blocks (bs>=NSB) return.
#define XCD_DECODE(NSB_, NSBP_, NOCG_)                 \
    int hb  = blockIdx.x;                              \
    int pos = hb % (8 * (NOCG_));                      \
    int xcd = pos % 8;                                 \
    int ocg = pos / 8;                                 \
    int sg8 = hb / (8 * (NOCG_));                      \
    int bs  = xcd * ((NSBP_) / 8) + sg8;               \
    if (bs >= (NSB_)) return;

// Intermediate layout: blocked channels ("c8 planes").
// bufK[plane][n][spatial][8] with plane = oc>>3. Each block writes ONLY its
// own plane -> every store is a dense 8-float chunk, consecutive threads
// adjacent -> full 128B cache lines. This kills the round-9 RMW disaster
// (WRITE 825MB vs 103MB output: 32B quarter-line writes from 4 different
// blocks + L2 eviction between them -> per-quarter sector writeback + line
// fetch. FETCH 77+4*103=489MB, WRITE 103*4*2=824MB -- both matched).

// =====================================================================
// conv1: 7x7 stride4 pad3, 3->32, fused BN+ReLU
// in : NCHW (256,3,224,224)   out: c8 planes (4, 256, 3136, 8)
// Thread: 8 oc x 4 images (n0, n0+64, n0+128, n0+192).  NOCG=4, NSB=784.
// Row loads: ix0=4*ox-3; ix0-1=4(ox-1) and ix0+3=4*ox both 16B-aligned ->
// two aligned float4 per (img,ic,ky): head (ox>0 only; .y/.z/.w) + tail.
// Rows iy<0 (oy==0, ky<3) skipped; bottom/right never OOB (pad<stride).
// =====================================================================
__global__ __launch_bounds__(256, 2) void conv1_bn_relu(
    const float* __restrict__ in, const float* __restrict__ w,
    const float* __restrict__ cb, const float* __restrict__ bsc,
    const float* __restrict__ bbi, const float* __restrict__ bmu,
    const float* __restrict__ bva, float* __restrict__ out)
{
    XCD_DECODE(784, 784, 4);
    __shared__ float wsm[1176]; // [ic][tap][oc8]
    int tid = threadIdx.x;
    for (int i = tid; i < 1176; i += 256) {
        int o = i & 7; int t = i >> 3;
        int ic = t / 49; int tap = t % 49;
        wsm[i] = w[(ocg * 8 + o) * 147 + ic * 49 + tap];
    }
    __syncthreads();

    int sg = bs * 256 + tid;          // [0, 200704)
    int n0 = sg / 3136;               // [0,64)
    int s  = sg - n0 * 3136;
    int oy = s / 56, ox = s - oy * 56;
    int iy0 = oy * 4 - 3, ix0 = ox * 4 - 3;
    bool headok = (ox > 0);

    float acc[4][8];
    #pragma unroll
    for (int i = 0; i < 4; ++i)
        #pragma unroll
        for (int o = 0; o < 8; ++o) acc[i][o] = 0.f;

    const size_t img = (size_t)3 * 224 * 224;
    const float* base0 = in + (size_t)n0 * img;

    for (int ic = 0; ic < 3; ++ic) {
        const float* xc = base0 + (size_t)ic * 224 * 224;
        const float* wc = wsm + ic * 49 * 8;
        #pragma unroll
        for (int ky = 0; ky < 7; ++ky) {
            bool rowok = (ky >= 3) || (oy > 0);
            if (rowok) {
                int iy = iy0 + ky;
                const float* xr = xc + iy * 224;
                float r[4][7];
                #pragma unroll
                for (int i = 0; i < 4; ++i) {
                    const float* xri = xr + (size_t)i * 64 * img;
                    float4 hd = make_float4(0.f, 0.f, 0.f, 0.f);
                    if (headok) hd = *(const float4*)(xri + ix0 - 1); // aligned
                    float4 tl = *(const float4*)(xri + ix0 + 3);      // aligned
                    r[i][0] = hd.y; r[i][1] = hd.z; r[i][2] = hd.w;
                    r[i][3] = tl.x; r[i][4] = tl.y; r[i][5] = tl.z; r[i][6] = tl.w;
                }
                #pragma unroll
                for (int kx = 0; kx < 7; ++kx) {
                    const float4* wv = (const float4*)(wc + (ky * 7 + kx) * 8);
                    float4 wa = wv[0], wb = wv[1];
                    float wr[8] = {wa.x, wa.y, wa.z, wa.w, wb.x, wb.y, wb.z, wb.w};
                    #pragma unroll
                    for (int i = 0; i < 4; ++i)
                        #pragma unroll
                        for (int o = 0; o < 8; ++o)
                            acc[i][o] = fmaf(r[i][kx], wr[o], acc[i][o]);
                }
            }
        }
    }

    float scale[8], shift[8];
    #pragma unroll
    for (int o = 0; o < 8; ++o) {
        int oc = ocg * 8 + o;
        scale[o] = bsc[oc] * rsqrtf(bva[oc] + BNEPS);
        shift[o] = (cb[oc] - bmu[oc]) * scale[o] + bbi[oc];
    }
    const size_t ps1 = (size_t)256 * 3136 * 8;   // plane stride
    #pragma unroll
    for (int i = 0; i < 4; ++i) {
        int n = n0 + 64 * i;
        float4 r0, r1;
        r0.x = fmaxf(fmaf(acc[i][0], scale[0], shift[0]), 0.f);
        r0.y = fmaxf(fmaf(acc[i][1], scale[1], shift[1]), 0.f);
        r0.z = fmaxf(fmaf(acc[i][2], scale[2], shift[2]), 0.f);
        r0.w = fmaxf(fmaf(acc[i][3], scale[3], shift[3]), 0.f);
        r1.x = fmaxf(fmaf(acc[i][4], scale[4], shift[4]), 0.f);
        r1.y = fmaxf(fmaf(acc[i][5], scale[5], shift[5]), 0.f);
        r1.z = fmaxf(fmaf(acc[i][6], scale[6], shift[6]), 0.f);
        r1.w = fmaxf(fmaf(acc[i][7], scale[7], shift[7]), 0.f);
        float* op = out + (size_t)ocg * ps1 + ((size_t)n * 3136 + s) * 8;
        *(float4*)(op)     = r0;   // dense 32B per thread, full lines per wave
        *(float4*)(op + 4) = r1;
    }
}

// =====================================================================
// generic 3x3 stride2 pad1 conv, c8-plane in / c8-plane out, fused BN+ReLU
// Thread: 8 oc x 4 images (n0, n0+64, n0+128, n0+192).
// Input channels icv*4..icv*4+3 live in plane icv>>1 at chunk offset (icv&1)*4.
// OOB only top/left: ok = ((ky>0)||(oy>0)) && ((kx>0)||(ox>0))
// =====================================================================
template<int IC, int IH, int IW, int OC, int OH, int OW, int NSB, int NSBP, int NOCG>
__global__ __launch_bounds__(256, 2) void conv3x3_bn_relu_c8(
    const float* __restrict__ in, const float* __restrict__ w,
    const float* __restrict__ cb, const float* __restrict__ bsc,
    const float* __restrict__ bbi, const float* __restrict__ bmu,
    const float* __restrict__ bva, float* __restrict__ out)
{
    constexpr int OCPT = 8;
    constexpr int WN = 9 * IC * OCPT;
    XCD_DECODE(NSB, NSBP, NOCG);
    __shared__ float wsm[WN];         // [tap][ic][oc8]
    int tid = threadIdx.x;
    for (int i = tid; i < WN; i += 256) {
        int o = i & 7; int t = i >> 3;
        int tap = t / IC; int ic = t % IC;
        wsm[i] = w[(size_t)(ocg * OCPT + o) * IC * 9 + ic * 9 + tap];
    }
    __syncthreads();

    int sg = bs * 256 + tid;
    int n0 = sg / (OH * OW);          // [0,64)
    int s  = sg - n0 * (OH * OW);
    int oy = s / OW, ox = s - oy * OW;
    int iy0 = oy * 2 - 1, ix0 = ox * 2 - 1;

    float acc[4][OCPT];
    #pragma unroll
    for (int i = 0; i < 4; ++i)
        #pragma unroll
        for (int o = 0; o < OCPT; ++o) acc[i][o] = 0.f;

    const size_t ihw  = (size_t)IH * IW;
    const size_t psin = (size_t)256 * ihw * 8;   // input plane stride

    #pragma unroll
    for (int ky = 0; ky < 3; ++ky) {
        #pragma unroll
        for (int kx = 0; kx < 3; ++kx) {
            bool ok = ((ky > 0) || (oy > 0)) && ((kx > 0) || (ox > 0));
            if (ok) {
                int iy = iy0 + ky, ix = ix0 + kx;
                const float* p0 = in + ((size_t)n0 * ihw + (size_t)iy * IW + ix) * 8;
                const float* wt0 = wsm + (ky * 3 + kx) * IC * OCPT;
                for (int icv = 0; icv < IC / 4; ++icv) {
                    const float* pp = p0 + (size_t)(icv >> 1) * psin + (icv & 1) * 4;
                    float4 v0 = *(const float4*)(pp);
                    float4 v1 = *(const float4*)(pp + 64 * ihw * 8);
                    float4 v2 = *(const float4*)(pp + 128 * ihw * 8);
                    float4 v3 = *(const float4*)(pp + 192 * ihw * 8);
                    float vi[4][4] = {{v0.x, v0.y, v0.z, v0.w},
                                      {v1.x, v1.y, v1.z, v1.w},
                                      {v2.x, v2.y, v2.z, v2.w},
                                      {v3.x, v3.y, v3.z, v3.w}};
                    #pragma unroll
                    for (int c = 0; c < 4; ++c) {
                        const float4* wt = (const float4*)(wt0 + (icv * 4 + c) * OCPT);
                        float4 wa = wt[0], wb = wt[1];
                        float wr[8] = {wa.x, wa.y, wa.z, wa.w, wb.x, wb.y, wb.z, wb.w};
                        #pragma unroll
                        for (int i = 0; i < 4; ++i)
                            #pragma unroll
                            for (int o = 0; o < 8; ++o)
                                acc[i][o] = fmaf(vi[i][c], wr[o], acc[i][o]);
                    }
                }
            }
        }
    }

    float scale[OCPT], shift[OCPT];
    #pragma unroll
    for (int o = 0; o < OCPT; ++o) {
        int oc = ocg * OCPT + o;
        scale[o] = bsc[oc] * rsqrtf(bva[oc] + BNEPS);
        shift[o] = (cb[oc] - bmu[oc]) * scale[o] + bbi[oc];
    }
    const size_t ohw   = (size_t)OH * OW;
    const size_t psout = (size_t)256 * ohw * 8;  // output plane stride
    #pragma unroll
    for (int i = 0; i < 4; ++i) {
        int n = n0 + 64 * i;
        float* op = out + (size_t)ocg * psout + ((size_t)n * ohw + s) * 8;
        float4 r0, r1;
        r0.x = fmaxf(fmaf(acc[i][0], scale[0], shift[0]), 0.f);
        r0.y = fmaxf(fmaf(acc[i][1], scale[1], shift[1]), 0.f);
        r0.z = fmaxf(fmaf(acc[i][2], scale[2], shift[2]), 0.f);
        r0.w = fmaxf(fmaf(acc[i][3], scale[3], shift[3]), 0.f);
        r1.x = fmaxf(fmaf(acc[i][4], scale[4], shift[4]), 0.f);
        r1.y = fmaxf(fmaf(acc[i][5], scale[5], shift[5]), 0.f);
        r1.z = fmaxf(fmaf(acc[i][6], scale[6], shift[6]), 0.f);
        r1.w = fmaxf(fmaf(acc[i][7], scale[7], shift[7]), 0.f);
        *(float4*)(op)     = r0;
        *(float4*)(op + 4) = r1;
    }
}

// =====================================================================
// avgpool c8 planes (16, 256, 196, 8) -> pooled (256,512),
// feature order f = c*4 + py*2 + px (reference reshape order)
// =====================================================================
__global__ __launch_bounds__(256) void pool_kernel(
    const float* __restrict__ in, float* __restrict__ out)
{
    int i = blockIdx.x * 256 + threadIdx.x;   // 131072 total
    int n = i >> 9; int f = i & 511;
    int c = f >> 2; int py = (f >> 1) & 1; int px = f & 1;
    const size_t ps3 = (size_t)256 * 196 * 8;
    const float* p = in + (size_t)(c >> 3) * ps3
                   + ((size_t)n * 196 + py * 7 * 14 + px * 7) * 8 + (c & 7);
    float sum = 0.f;
    #pragma unroll
    for (int dy = 0; dy < 7; ++dy)
        #pragma unroll
        for (int dx = 0; dx < 7; ++dx) sum += p[(dy * 14 + dx) * 8];
    out[i] = sum * (1.f / 49.f);
}

// =====================================================================
// head: pre-linear + tanh*pi + 4-qubit statevector sim + post1/post2
// one wave (64 lanes) per image
// =====================================================================
__device__ __forceinline__ void q_ry(float2* st, int q, float t) {
    float s, c; sincosf(0.5f * t, &s, &c);
    int m = 1 << (3 - q);
    #pragma unroll
    for (int i = 0; i < 16; ++i) {
        if (!(i & m)) {
            float2 a0 = st[i], a1 = st[i | m];
            st[i]     = make_float2(c * a0.x - s * a1.x, c * a0.y - s * a1.y);
            st[i | m] = make_float2(s * a0.x + c * a1.x, s * a0.y + c * a1.y);
        }
    }
}
__device__ __forceinline__ void q_rx(float2* st, int q, float t) {
    float s, c; sincosf(0.5f * t, &s, &c);
    int m = 1 << (3 - q);
    #pragma unroll
    for (int i = 0; i < 16; ++i) {
        if (!(i & m)) {
            float2 a0 = st[i], a1 = st[i | m];
            st[i]     = make_float2(c * a0.x + s * a1.y, c * a0.y - s * a1.x);
            st[i | m] = make_float2(s * a0.y + c * a1.x, -s * a0.x + c * a1.y);
        }
    }
}
__device__ __forceinline__ void q_rz(float2* st, int q, float t) {
    float s, c; sincosf(0.5f * t, &s, &c);
    int m = 1 << (3 - q);
    #pragma unroll
    for (int i = 0; i < 16; ++i) {
        float2 a = st[i];
        if (i & m)  st[i] = make_float2(a.x * c - a.y * s, a.y * c + a.x * s);
        else        st[i] = make_float2(a.x * c + a.y * s, a.y * c - a.x * s);
    }
}
__device__ __forceinline__ void q_cnot(float2* st, int c, int t) {
    int mc = 1 << (3 - c), mt = 1 << (3 - t);
    #pragma unroll
    for (int i = 0; i < 16; ++i) {
        if ((i & mc) && !(i & mt)) {
            float2 tmp = st[i]; st[i] = st[i | mt]; st[i | mt] = tmp;
        }
    }
}

__global__ __launch_bounds__(64) void head_kernel(
    const float* __restrict__ h,      // (256,512)
    const float* __restrict__ pre_w, const float* __restrict__ pre_b,
    const float* __restrict__ qw,     // (2,4,3)
    const float* __restrict__ p1w, const float* __restrict__ p1b,
    const float* __restrict__ p2w, const float* __restrict__ p2b,
    float* __restrict__ out)
{
    int n = blockIdx.x;
    int lane = threadIdx.x;
    const float* hb = h + (size_t)n * 512;

    float part[4] = {0.f, 0.f, 0.f, 0.f};
    #pragma unroll
    for (int j = 0; j < 8; ++j) {
        int idx = lane * 8 + j;
        float hv = hb[idx];
        #pragma unroll
        for (int o = 0; o < 4; ++o)
            part[o] = fmaf(hv, pre_w[o * 512 + idx], part[o]);
    }
    #pragma unroll
    for (int o = 0; o < 4; ++o) {
        float p = part[o];
        #pragma unroll
        for (int off = 32; off >= 1; off >>= 1) p += __shfl_xor(p, off);
        part[o] = p;
    }
    float ang[4];
    #pragma unroll
    for (int o = 0; o < 4; ++o)
        ang[o] = tanhf(part[o] + pre_b[o]) * 3.14159265358979323846f;

    // 4-qubit statevector sim (all lanes redundantly; wave-uniform)
    float2 st[16];
    #pragma unroll
    for (int i = 0; i < 16; ++i) st[i] = make_float2(0.f, 0.f);
    st[0] = make_float2(1.f, 0.f);
    #pragma unroll
    for (int q = 0; q < 4; ++q) q_ry(st, q, ang[q]);
    #pragma unroll
    for (int l = 0; l < 2; ++l) {
        #pragma unroll
        for (int q = 0; q < 4; ++q) {
            q_rx(st, q, qw[(l * 4 + q) * 3 + 0]);
            q_ry(st, q, qw[(l * 4 + q) * 3 + 1]);
            q_rz(st, q, qw[(l * 4 + q) * 3 + 2]);
        }
        #pragma unroll
        for (int q = 0; q < 3; ++q) q_cnot(st, q, q + 1);
    }
    float ev[4];
    #pragma unroll
    for (int q = 0; q < 4; ++q) {
        int m = 1 << (3 - q);
        float e = 0.f;
        #pragma unroll
        for (int i = 0; i < 16; ++i) {
            float p = st[i].x * st[i].x + st[i].y * st[i].y;
            e += (i & m) ? -p : p;
        }
        ev[q] = e;
    }

    // post1 row per lane, relu
    float y = p1b[lane];
    #pragma unroll
    for (int o = 0; o < 4; ++o) y = fmaf(ev[o], p1w[lane * 4 + o], y);
    y = fmaxf(y, 0.f);

    // post2: 5 wave reductions
    float o5[5];
    #pragma unroll
    for (int k = 0; k < 5; ++k) {
        float p = y * p2w[k * 64 + lane];
        #pragma unroll
        for (int off = 32; off >= 1; off >>= 1) p += __shfl_xor(p, off);
        o5[k] = p;
    }
    if (lane == 0) {
        #pragma unroll
        for (int k = 0; k < 5; ++k) out[n * 5 + k] = o5[k] + p2b[k];
    }
}

// =====================================================================
extern "C" void kernel_launch(void* const* d_in, const int* in_sizes, int n_in,
                              void* d_out, int out_size, void* d_ws, size_t ws_size,
                              hipStream_t stream)
{
    const float* x   = (const float*)d_in[0];
    const float* c1w = (const float*)d_in[1];
    const float* c1b = (const float*)d_in[2];
    const float* b1s = (const float*)d_in[3];
    const float* b1b = (const float*)d_in[4];
    const float* b1m = (const float*)d_in[5];
    const float* b1v = (const float*)d_in[6];
    const float* c2w = (const float*)d_in[7];
    const float* c2b = (const float*)d_in[8];
    const float* b2s = (const float*)d_in[9];
    const float* b2b = (const float*)d_in[10];
    const float* b2m = (const float*)d_in[11];
    const float* b2v = (const float*)d_in[12];
    const float* c3w = (const float*)d_in[13];
    const float* c3b = (const float*)d_in[14];
    const float* b3s = (const float*)d_in[15];
    const float* b3b = (const float*)d_in[16];
    const float* b3m = (const float*)d_in[17];
    const float* b3v = (const float*)d_in[18];
    const float* prw = (const float*)d_in[19];
    const float* prb = (const float*)d_in[20];
    const float* qw  = (const float*)d_in[21];
    const float* p1w = (const float*)d_in[22];
    const float* p1b = (const float*)d_in[23];
    const float* p2w = (const float*)d_in[24];
    const float* p2b = (const float*)d_in[25];

    float* buf1   = (float*)d_ws;                              // c8 planes (4,256,3136,8)
    float* buf2   = buf1 + (size_t)256 * 3136 * 32;            // c8 planes (8,256,784,8)
    float* buf3   = (float*)d_ws;                              // reuse: c8 planes (16,256,196,8)
    float* pooled = buf3 + (size_t)256 * 196 * 128;            // (256,512)
    float* outp   = (float*)d_out;

    // conv1: NSB = 64*3136/256 = 784 (%8==0), NOCG=4 -> grid 3136
    hipLaunchKernelGGL(conv1_bn_relu, dim3(784 * 4), dim3(256), 0, stream,
                       x, c1w, c1b, b1s, b1b, b1m, b1v, buf1);

    // conv2: 32->64.  NSB = 64*784/256 = 196 -> NSBP=200, NOCG = 64/8 = 8
    hipLaunchKernelGGL((conv3x3_bn_relu_c8<32, 56, 56, 64, 28, 28, 196, 200, 8>),
                       dim3(200 * 8), dim3(256), 0, stream,
                       buf1, c2w, c2b, b2s, b2b, b2m, b2v, buf2);

    // conv3: 64->128.  NSB = 64*196/256 = 49 -> NSBP=56, NOCG = 128/8 = 16
    hipLaunchKernelGGL((conv3x3_bn_relu_c8<64, 28, 28, 128, 14, 14, 49, 56, 16>),
                       dim3(56 * 16), dim3(256), 0, stream,
                       buf2, c3w, c3b, b3s, b3b, b3m, b3v, buf3);

    // pool: c8 planes -> (256,512) reference order
    hipLaunchKernelGGL(pool_kernel, dim3(131072 / 256), dim3(256), 0, stream,
                       buf3, pooled);

    // head: one wave per image
    hipLaunchKernelGGL(head_kernel, dim3(256), dim3(64), 0, stream,
                       pooled, prw, prb, qw, p1w, p1b, p2w, p2b, outp);
}